// Round 1
// baseline (3752.282 us; speedup 1.0000x reference)
//
#include <hip/hip_runtime.h>
#include <math.h>

// ---- problem constants ----
#define Bn   8192
#define Fn   20
#define Vn   1000
#define En   32
#define NDn  10
#define INP0 960        // (F+ND)*E
#define Tn   2
#define Kn   4
#define Sn   4
#define Dn   512
#define Hn   256
#define NE   12         // T*K + S experts
#define TEMP_INV 0.5f   // 1/TEMP

// ---- GEMM tiling ----
#define BM 64
#define BD 64
#define BK 16

__device__ __forceinline__ float f4c(const float4& v, int i) {
  return (i == 0) ? v.x : (i == 1) ? v.y : (i == 2) ? v.z : v.w;
}

// ======================= embedding + dense projection =======================
// out[b, 0:640]   = emb_tables[f, sparse[b,f], e]   (c = f*32+e)
// out[b, 640:960] = dense_features[b,:] @ dense_W + dense_b
__global__ __launch_bounds__(256) void embed_kernel(
    const int* __restrict__ sparse, const float* __restrict__ dense,
    const float* __restrict__ emb, const float* __restrict__ dW,
    const float* __restrict__ db, float* __restrict__ out)
{
  int b = blockIdx.x;
  int tid = threadIdx.x;
  __shared__ float dfs[NDn];
  if (tid < NDn) dfs[tid] = dense[b * NDn + tid];
  __syncthreads();
  for (int c = tid; c < INP0; c += 256) {
    float v;
    if (c < Fn * En) {
      int f = c >> 5, e = c & 31;
      int idx = sparse[b * Fn + f];
      v = emb[((size_t)f * Vn + idx) * En + e];
    } else {
      int j = c - Fn * En;
      float a = db[j];
#pragma unroll
      for (int d = 0; d < NDn; ++d) a += dfs[d] * dW[d * (NDn * En) + j];
      v = a;
    }
    out[(size_t)b * INP0 + c] = v;
  }
}

// ======================= gate kernel =======================
// gates[b, t*8+eg] = softmax_eg( (x[b,:]@Wg[t,:,eg] + bg[t,eg]) / TEMP )
// one wave per row; lane = slice*16 + t*8 + eg
template <int IN>
__global__ __launch_bounds__(256) void gate_kernel(
    const float* __restrict__ x, const float* __restrict__ Wg,
    const float* __restrict__ bg, float* __restrict__ gates)
{
  int tid = threadIdx.x;
  int wv = tid >> 6, lane = tid & 63;
  int b = blockIdx.x * 4 + wv;
  int e = lane & 15;          // t*8 + eg
  int t = e >> 3, eg = e & 7;
  int slice = lane >> 4;      // 0..3 K-slices
  const float* xr = x + (size_t)b * IN;
  const float* wr = Wg + (size_t)t * IN * 8 + eg;
  float p = 0.f;
  for (int i = slice; i < IN; i += 4) p += xr[i] * wr[(size_t)i * 8];
  p += __shfl_xor(p, 32);
  p += __shfl_xor(p, 16);     // now every lane has full dot for its e
  float z = (p + bg[t * 8 + eg]) * TEMP_INV;
  float m = z;
  m = fmaxf(m, __shfl_xor(m, 1));
  m = fmaxf(m, __shfl_xor(m, 2));
  m = fmaxf(m, __shfl_xor(m, 4));
  float ex = expf(z - m);
  float s = ex;
  s += __shfl_xor(s, 1);
  s += __shfl_xor(s, 2);
  s += __shfl_xor(s, 4);
  if (lane < 16) gates[(size_t)b * 16 + lane] = ex / s;
}

// ======================= fused PLE layer =======================
// Computes, for a 64-row x 64-col tile of d, all 12 experts:
//   expert_e[b,d] = relu(x[b,:] @ W_e[:,d] + bias_e[d])
// then applies softmaxed gates and writes either
//   xmean[b,d]  = 0.5*(tout[b,0,d] + tout[b,1,d])     (layers 0,1)
// or tout[b,t,d]                                       (layer 2)
// Experts 0..7 = task (t = e>>2, k = e&3); experts 8..11 = shared.
template <int IN>
__global__ __launch_bounds__(512, 1) void ple_layer(
    const float* __restrict__ x,
    const float* __restrict__ Wt, const float* __restrict__ bt,
    const float* __restrict__ Ws, const float* __restrict__ bs,
    const float* __restrict__ gates,
    float* __restrict__ xmean, float* __restrict__ tout)
{
  static_assert(IN % BK == 0, "IN % BK");
  __shared__ float xs[BK][BM + 2];   // +2 pad: conflict-free writes
  __shared__ float ws[BK][NE][BD];   // 48 KB
  __shared__ float gsh[BM][16];

  int tid = threadIdx.x;
  int tx = tid & 15;        // d-quad index (4 contiguous d each)
  int ty = tid >> 4;        // 0..31, rows ty and ty+32
  int d0 = blockIdx.x * BD;
  int b0 = blockIdx.y * BM;

  // stage gates for the 64 rows
#pragma unroll
  for (int r = 0; r < 2; ++r) {
    int li = tid + r * 512;          // 0..1023
    int bl = li >> 4, c = li & 15;
    gsh[bl][c] = gates[(size_t)(b0 + bl) * 16 + c];
  }

  float acc[2][NE][4];
#pragma unroll
  for (int a = 0; a < 2; ++a)
#pragma unroll
    for (int e = 0; e < NE; ++e)
#pragma unroll
      for (int j = 0; j < 4; ++j) acc[a][e][j] = 0.f;

  const int nk = IN / BK;
  for (int kk = 0; kk < nk; ++kk) {
    int i0 = kk * BK;
    // x tile: 16x64, 2 elems/thread
#pragma unroll
    for (int r = 0; r < 2; ++r) {
      int li = tid + r * 512;
      int bl = li >> 4, k = li & 15;
      xs[k][bl] = x[(size_t)(b0 + bl) * IN + i0 + k];
    }
    // W tile: 16 x 12 x 64 floats = 3072 float4, 6/thread
#pragma unroll
    for (int r = 0; r < 6; ++r) {
      int f = tid + r * 512;         // 0..3071
      int d4 = f & 15;
      int row = f >> 4;              // 0..191 = k*12+e
      int k = row / NE;
      int e = row - k * NE;
      const float* base = (e < 8) ? (Wt + (size_t)e * IN * Dn)
                                  : (Ws + (size_t)(e - 8) * IN * Dn);
      float4 v = *(const float4*)(base + (size_t)(i0 + k) * Dn + d0 + 4 * d4);
      *(float4*)&ws[k][e][4 * d4] = v;
    }
    __syncthreads();
#pragma unroll 2
    for (int k = 0; k < BK; ++k) {
      float xa = xs[k][ty];
      float xb = xs[k][ty + 32];
#pragma unroll
      for (int e = 0; e < NE; ++e) {
        float4 w = *(const float4*)&ws[k][e][4 * tx];
        acc[0][e][0] += xa * w.x; acc[0][e][1] += xa * w.y;
        acc[0][e][2] += xa * w.z; acc[0][e][3] += xa * w.w;
        acc[1][e][0] += xb * w.x; acc[1][e][1] += xb * w.y;
        acc[1][e][2] += xb * w.z; acc[1][e][3] += xb * w.w;
      }
    }
    __syncthreads();
  }

  // epilogue: bias + relu + gated combine
#pragma unroll
  for (int bb = 0; bb < 2; ++bb) {
    int bl = ty + bb * 32;
    int b = b0 + bl;
    float to0[4] = {0.f, 0.f, 0.f, 0.f};
    float to1[4] = {0.f, 0.f, 0.f, 0.f};
#pragma unroll
    for (int e = 0; e < NE; ++e) {
      const float* bp = (e < 8) ? (bt + (size_t)e * Dn) : (bs + (size_t)(e - 8) * Dn);
      float4 bv = *(const float4*)(bp + d0 + 4 * tx);
      float gt0, gt1;
      if (e < 8) {
        int t = e >> 2, k = e & 3;
        float g = gsh[bl][t * 8 + k];
        gt0 = (t == 0) ? g : 0.f;
        gt1 = (t == 1) ? g : 0.f;
      } else {
        int s = e - 8;
        gt0 = gsh[bl][4 + s];
        gt1 = gsh[bl][8 + 4 + s];
      }
#pragma unroll
      for (int j = 0; j < 4; ++j) {
        float v = acc[bb][e][j] + f4c(bv, j);
        v = fmaxf(v, 0.f);
        to0[j] += gt0 * v;
        to1[j] += gt1 * v;
      }
    }
    if (tout) {
      *(float4*)&tout[(size_t)b * (2 * Dn) + d0 + 4 * tx] =
          make_float4(to0[0], to0[1], to0[2], to0[3]);
      *(float4*)&tout[(size_t)b * (2 * Dn) + Dn + d0 + 4 * tx] =
          make_float4(to1[0], to1[1], to1[2], to1[3]);
    } else {
      *(float4*)&xmean[(size_t)b * Dn + d0 + 4 * tx] =
          make_float4(0.5f * (to0[0] + to1[0]), 0.5f * (to0[1] + to1[1]),
                      0.5f * (to0[2] + to1[2]), 0.5f * (to0[3] + to1[3]));
    }
  }
}

// ======================= tower =======================
// per (b,t): h1 = relu(BN(tout@tw1 + tb1)); h2 = relu(h1@tw2 + tb2);
// logit = h2 . tw3 + tb3; out = [ctr, ctr*cvr, ctr*cvr] stacked (3,B)
__global__ __launch_bounds__(256) void tower_kernel(
    const float* __restrict__ tout,
    const float* __restrict__ tw1, const float* __restrict__ tb1,
    const float* __restrict__ bng, const float* __restrict__ bnb,
    const float* __restrict__ bnm, const float* __restrict__ bnv,
    const float* __restrict__ tw2, const float* __restrict__ tb2,
    const float* __restrict__ tw3, const float* __restrict__ tb3,
    float* __restrict__ out)
{
  __shared__ float xsh[8][2 * Dn];        // 32 KB
  __shared__ float h1s[8][2 * Hn];        // 16 KB
  __shared__ float h2s[8][Hn];            // 8 KB  ([bb][t*128+g])
  __shared__ float lg[8][2];
  int tid = threadIdx.x;
  int b0 = blockIdx.x * 8;

#pragma unroll
  for (int r = 0; r < 32; ++r) {
    int li = tid + r * 256;
    int bb = li >> 10, c = li & 1023;
    xsh[bb][c] = tout[(size_t)(b0 + bb) * 1024 + c];
  }
  __syncthreads();

  // ---- h1: thread j handles output h=j for both tasks, 8 rows ----
  {
    int j = tid;
    float acc[2][8];
#pragma unroll
    for (int t = 0; t < 2; ++t)
#pragma unroll
      for (int bb = 0; bb < 8; ++bb) acc[t][bb] = 0.f;
    for (int d4 = 0; d4 < Dn / 4; ++d4) {
      int d = d4 * 4;
      float4 xa[8], xb[8];
#pragma unroll
      for (int bb = 0; bb < 8; ++bb) {
        xa[bb] = *(const float4*)&xsh[bb][d];
        xb[bb] = *(const float4*)&xsh[bb][Dn + d];
      }
#pragma unroll
      for (int dd = 0; dd < 4; ++dd) {
        float w0 = tw1[(size_t)(d + dd) * Hn + j];
        float w1 = tw1[(size_t)Dn * Hn + (size_t)(d + dd) * Hn + j];
#pragma unroll
        for (int bb = 0; bb < 8; ++bb) {
          acc[0][bb] += f4c(xa[bb], dd) * w0;
          acc[1][bb] += f4c(xb[bb], dd) * w1;
        }
      }
    }
#pragma unroll
    for (int t = 0; t < 2; ++t) {
      float mu = bnm[t * Hn + j], var = bnv[t * Hn + j];
      float inv = rsqrtf(var + 1e-5f) * bng[t * Hn + j];
      float be = bnb[t * Hn + j];
      float bias = tb1[t * Hn + j];
#pragma unroll
      for (int bb = 0; bb < 8; ++bb) {
        float h = acc[t][bb] + bias;
        h = (h - mu) * inv + be;
        h1s[bb][t * Hn + j] = fmaxf(h, 0.f);
      }
    }
  }
  __syncthreads();

  // ---- h2: thread = (t = tid>>7, g = tid&127) ----
  {
    int t = tid >> 7, g = tid & 127;
    float acc2[8];
#pragma unroll
    for (int bb = 0; bb < 8; ++bb) acc2[bb] = 0.f;
    for (int h4 = 0; h4 < Hn / 4; ++h4) {
      float4 hv[8];
#pragma unroll
      for (int bb = 0; bb < 8; ++bb)
        hv[bb] = *(const float4*)&h1s[bb][t * Hn + h4 * 4];
#pragma unroll
      for (int dd = 0; dd < 4; ++dd) {
        float w = tw2[(size_t)t * Hn * 128 + (size_t)(h4 * 4 + dd) * 128 + g];
#pragma unroll
        for (int bb = 0; bb < 8; ++bb) acc2[bb] += f4c(hv[bb], dd) * w;
      }
    }
    float bias = tb2[t * 128 + g];
#pragma unroll
    for (int bb = 0; bb < 8; ++bb)
      h2s[bb][t * 128 + g] = fmaxf(acc2[bb] + bias, 0.f);
  }
  __syncthreads();

  // ---- logits: 16 (bb,t) pairs, 4 per wave ----
  {
    int wv = tid >> 6, lane = tid & 63;
#pragma unroll
    for (int p = 0; p < 4; ++p) {
      int idx = wv * 4 + p;
      int bb = idx >> 1, t = idx & 1;
      float v = h2s[bb][t * 128 + lane] * tw3[t * 128 + lane] +
                h2s[bb][t * 128 + 64 + lane] * tw3[t * 128 + 64 + lane];
      v += __shfl_xor(v, 1);  v += __shfl_xor(v, 2);  v += __shfl_xor(v, 4);
      v += __shfl_xor(v, 8);  v += __shfl_xor(v, 16); v += __shfl_xor(v, 32);
      if (lane == 0) lg[bb][t] = v + tb3[t];
    }
  }
  __syncthreads();

  if (tid < 8) {
    int b = b0 + tid;
    float ctr = 1.f / (1.f + expf(-lg[tid][0]));
    float cvr = 1.f / (1.f + expf(-lg[tid][1]));
    float cc = ctr * cvr;
    out[b] = ctr;
    out[Bn + b] = cc;
    out[2 * Bn + b] = cc;
  }
}

// ======================= launch =======================
extern "C" void kernel_launch(void* const* d_in, const int* in_sizes, int n_in,
                              void* d_out, int out_size, void* d_ws, size_t ws_size,
                              hipStream_t stream) {
  const int* sparse   = (const int*)d_in[0];
  const float* dense  = (const float*)d_in[1];
  const float* emb    = (const float*)d_in[2];
  const float* dW     = (const float*)d_in[3];
  const float* db     = (const float*)d_in[4];
  const float* Wt[3]  = {(const float*)d_in[5],  (const float*)d_in[11], (const float*)d_in[17]};
  const float* btb[3] = {(const float*)d_in[6],  (const float*)d_in[12], (const float*)d_in[18]};
  const float* Wsh[3] = {(const float*)d_in[7],  (const float*)d_in[13], (const float*)d_in[19]};
  const float* bsh[3] = {(const float*)d_in[8],  (const float*)d_in[14], (const float*)d_in[20]};
  const float* Wg[3]  = {(const float*)d_in[9],  (const float*)d_in[15], (const float*)d_in[21]};
  const float* bg[3]  = {(const float*)d_in[10], (const float*)d_in[16], (const float*)d_in[22]};
  const float* tw1 = (const float*)d_in[23];
  const float* tb1 = (const float*)d_in[24];
  const float* bng = (const float*)d_in[25];
  const float* bnb = (const float*)d_in[26];
  const float* bnm = (const float*)d_in[27];
  const float* bnv = (const float*)d_in[28];
  const float* tw2 = (const float*)d_in[29];
  const float* tb2 = (const float*)d_in[30];
  const float* tw3 = (const float*)d_in[31];
  const float* tb3 = (const float*)d_in[32];

  // workspace layout (floats): embed | x1 | tout | gates ; x2 reuses embed
  float* wsf    = (float*)d_ws;
  float* embedB = wsf;                               // B*960
  float* x1     = embedB + (size_t)Bn * INP0;        // B*512
  float* toutB  = x1 + (size_t)Bn * Dn;              // B*1024
  float* gatesB = toutB + (size_t)Bn * 2 * Dn;       // B*16
  float* x2     = embedB;                            // reuse (embed dead after layer 0)

  dim3 gGrid(Bn / 4);
  dim3 pGrid(Dn / BD, Bn / BM);

  embed_kernel<<<Bn, 256, 0, stream>>>(sparse, dense, emb, dW, db, embedB);

  gate_kernel<INP0><<<gGrid, 256, 0, stream>>>(embedB, Wg[0], bg[0], gatesB);
  ple_layer<INP0><<<pGrid, 512, 0, stream>>>(embedB, Wt[0], btb[0], Wsh[0], bsh[0],
                                             gatesB, x1, nullptr);

  gate_kernel<Dn><<<gGrid, 256, 0, stream>>>(x1, Wg[1], bg[1], gatesB);
  ple_layer<Dn><<<pGrid, 512, 0, stream>>>(x1, Wt[1], btb[1], Wsh[1], bsh[1],
                                           gatesB, x2, nullptr);

  gate_kernel<Dn><<<gGrid, 256, 0, stream>>>(x2, Wg[2], bg[2], gatesB);
  ple_layer<Dn><<<pGrid, 512, 0, stream>>>(x2, Wt[2], btb[2], Wsh[2], bsh[2],
                                           gatesB, nullptr, toutB);

  tower_kernel<<<Bn / 8, 256, 0, stream>>>(toutB, tw1, tb1, bng, bnb, bnm, bnv,
                                           tw2, tb2, tw3, tb3, (float*)d_out);
}

// Round 2
// 491.817 us; speedup vs baseline: 7.6294x; 7.6294x over previous
//
#include <hip/hip_runtime.h>
#include <math.h>

#define Bn 8192
#define INP0 960
#define Dn 512
#define Hn 256
#define TEMP_INV 0.5f

typedef __attribute__((ext_vector_type(8))) short short8;
typedef __attribute__((ext_vector_type(8))) unsigned short ushort8;
typedef __attribute__((ext_vector_type(4))) float f32x4;

__device__ __forceinline__ int swz(int x) { return x ^ ((x >> 3) & 0x70); }

__device__ __forceinline__ unsigned short f2bf(float f) {
  unsigned u = __builtin_bit_cast(unsigned, f);
  u += 0x7FFF + ((u >> 16) & 1);
  return (unsigned short)(u >> 16);
}
__device__ __forceinline__ float bf2f(unsigned short s) {
  unsigned u = ((unsigned)s) << 16;
  return __builtin_bit_cast(float, u);
}
__device__ __forceinline__ void gload16(const void* g, void* l) {
  __builtin_amdgcn_global_load_lds(
      (const __attribute__((address_space(1))) unsigned int*)g,
      (__attribute__((address_space(3))) unsigned int*)l, 16, 0, 0);
}
__device__ __forceinline__ float f4c(const float4& v, int i) {
  return (i == 0) ? v.x : (i == 1) ? v.y : (i == 2) ? v.z : v.w;
}

// ============ weight convert: fp32 (e,k,d) -> bf16 tiled/swizzled [kk][dblk][e][4KB] ============
template <int IN>
__global__ __launch_bounds__(256) void conv_w(const float* __restrict__ Wt,
                                              const float* __restrict__ Ws,
                                              unsigned short* __restrict__ Wbt) {
  __shared__ float T[64][33];
  int kk = blockIdx.x, dblk = blockIdx.y, e = blockIdx.z;
  int t = threadIdx.x;
  const float* base = (e < 8) ? (Wt + (size_t)e * IN * Dn) : (Ws + (size_t)(e - 8) * IN * Dn);
  int k = t >> 3, dq = t & 7;
  const float* gp = base + (size_t)(kk * 32 + k) * Dn + dblk * 64 + dq * 8;
  float4 v0 = *(const float4*)gp, v1 = *(const float4*)(gp + 4);
  T[dq * 8 + 0][k] = v0.x; T[dq * 8 + 1][k] = v0.y; T[dq * 8 + 2][k] = v0.z; T[dq * 8 + 3][k] = v0.w;
  T[dq * 8 + 4][k] = v1.x; T[dq * 8 + 5][k] = v1.y; T[dq * 8 + 6][k] = v1.z; T[dq * 8 + 7][k] = v1.w;
  __syncthreads();
  int L = t * 16;
  int nat = swz(L);
  int d = nat >> 6, k0 = (nat & 63) >> 1;
  ushort8 o;
#pragma unroll
  for (int u = 0; u < 8; ++u) o[u] = f2bf(T[d][k0 + u]);
  *(ushort8*)(Wbt + (((size_t)(kk * 8 + dblk) * 12 + e) << 11) + (L >> 1)) = o;
}

// ============ embedding: writes natural bf16 x0n and tiled/swizzled x0t ============
__global__ __launch_bounds__(256) void embed_kernel(
    const int* __restrict__ sparse, const float* __restrict__ dense,
    const float* __restrict__ emb, const float* __restrict__ dW,
    const float* __restrict__ db,
    unsigned short* __restrict__ xn, unsigned short* __restrict__ xt) {
  int b = blockIdx.x, t = threadIdx.x;
  __shared__ float dfs[10];
  if (t < 10) dfs[t] = dense[b * 10 + t];
  __syncthreads();
  if (t >= 240) return;
  int c = t * 4;
  float v[4];
  if (c < 640) {
    int f = c >> 5, e0 = c & 31;
    int idx = sparse[b * 20 + f];
    const float* ep = emb + ((size_t)f * 1000 + idx) * 32 + e0;
    float4 q = *(const float4*)ep;
    v[0] = q.x; v[1] = q.y; v[2] = q.z; v[3] = q.w;
  } else {
    int j = c - 640;
#pragma unroll
    for (int u = 0; u < 4; ++u) {
      float a = db[j + u];
#pragma unroll
      for (int d = 0; d < 10; ++d) a += dfs[d] * dW[d * 320 + j + u];
      v[u] = a;
    }
  }
  ushort4 pk;
  pk.x = f2bf(v[0]); pk.y = f2bf(v[1]); pk.z = f2bf(v[2]); pk.w = f2bf(v[3]);
  *(ushort4*)(xn + (size_t)b * 960 + c) = pk;
  int kk = c >> 5, bblk = b >> 6;
  int nat = ((b & 63) << 6) + ((c & 31) << 1);
  *(ushort4*)(xt + (((size_t)kk * 128 + bblk) << 11) + (swz(nat) >> 1)) = pk;
}

// ============ gates (reads natural bf16 x) ============
template <int IN>
__global__ __launch_bounds__(256) void gate_kernel(
    const unsigned short* __restrict__ x, const float* __restrict__ Wg,
    const float* __restrict__ bg, float* __restrict__ gates) {
  int tid = threadIdx.x;
  int wv = tid >> 6, lane = tid & 63;
  int b = blockIdx.x * 4 + wv;
  int e = lane & 15, t = e >> 3, eg = e & 7;
  int slice = lane >> 4;
  const unsigned short* xr = x + (size_t)b * IN;
  const float* wr = Wg + (size_t)t * IN * 8 + eg;
  float p = 0.f;
  for (int i = slice * (IN / 4); i < (slice + 1) * (IN / 4); i += 4) {
    ushort4 xv = *(const ushort4*)(xr + i);
    p += bf2f(xv.x) * wr[(size_t)(i + 0) * 8];
    p += bf2f(xv.y) * wr[(size_t)(i + 1) * 8];
    p += bf2f(xv.z) * wr[(size_t)(i + 2) * 8];
    p += bf2f(xv.w) * wr[(size_t)(i + 3) * 8];
  }
  p += __shfl_xor(p, 32);
  p += __shfl_xor(p, 16);
  float z = (p + bg[t * 8 + eg]) * TEMP_INV;
  float m = z;
  m = fmaxf(m, __shfl_xor(m, 1)); m = fmaxf(m, __shfl_xor(m, 2)); m = fmaxf(m, __shfl_xor(m, 4));
  float ex = expf(z - m);
  float s = ex;
  s += __shfl_xor(s, 1); s += __shfl_xor(s, 2); s += __shfl_xor(s, 4);
  if (lane < 16) gates[(size_t)b * 16 + lane] = ex / s;
}

// ============ fused PLE layer: 12 waves, expert-per-wave, MFMA, in-LDS gated combine ============
#define BUFSZ 53248
#define XOFF 49152
#define GSH_OFF 106496
#define OUTS_OFF 110592
// smem total = 110592 + 2*64*72*2 = 129024

template <int IN, int MODE>
__global__ __launch_bounds__(768) void ple_mfma(
    const unsigned short* __restrict__ xt, const float* __restrict__ gates,
    const unsigned short* __restrict__ Wbt,
    const float* __restrict__ btb, const float* __restrict__ bsh,
    unsigned short* __restrict__ outn, unsigned short* __restrict__ outt) {
  __shared__ __align__(16) char smem[129024];
  const int NKv = IN / 32;
  int tid = threadIdx.x;
  int wv = tid >> 6, lane = tid & 63;
  int r = lane & 15, g = lane >> 4;
  int bblk = blockIdx.x, dblk = blockIdx.y;
  int b0 = bblk * 64, d0 = dblk * 64;

  if (tid < 256)
    *(float4*)(smem + GSH_OFF + tid * 16) = *(const float4*)(gates + (size_t)b0 * 16 + tid * 4);

  f32x4 acc[4][4];
#pragma unroll
  for (int i = 0; i < 4; ++i)
#pragma unroll
    for (int j = 0; j < 4; ++j) acc[i][j] = f32x4{0.f, 0.f, 0.f, 0.f};

  const char* wchunk = (const char*)Wbt + (size_t)dblk * 49152;
  const char* xchunk = (const char*)xt + (size_t)bblk * 4096;

  {  // prologue: stage kk=0 into buf0
    char* lb = smem;
#pragma unroll
    for (int i = 0; i < 4; ++i)
      gload16(wchunk + tid * 16 + i * 12288, lb + tid * 16 + i * 12288);
    if (tid < 256) gload16(xchunk + tid * 16, lb + XOFF + tid * 16);
  }
  __syncthreads();

  int cur = 0;
  for (int kk = 0; kk < NKv; ++kk) {
    if (kk + 1 < NKv) {
      const char* ws = wchunk + (size_t)(kk + 1) * 8 * 49152;
      const char* xs = xchunk + (size_t)(kk + 1) * 128 * 4096;
      char* lb = smem + (cur ^ 1) * BUFSZ;
#pragma unroll
      for (int i = 0; i < 4; ++i)
        gload16(ws + tid * 16 + i * 12288, lb + tid * 16 + i * 12288);
      if (tid < 256) gload16(xs + tid * 16, lb + XOFF + tid * 16);
    }
    {
      const char* lb = smem + cur * BUFSZ;
      const char* xb = lb + XOFF;
      const char* wb = lb + (wv << 12);
      short8 a[4], bfr[4];
#pragma unroll
      for (int rt = 0; rt < 4; ++rt)
        a[rt] = *(const short8*)(xb + swz(((rt * 16 + r) << 6) + (g << 4)));
#pragma unroll
      for (int ct = 0; ct < 4; ++ct)
        bfr[ct] = *(const short8*)(wb + swz(((ct * 16 + r) << 6) + (g << 4)));
#pragma unroll
      for (int rt = 0; rt < 4; ++rt)
#pragma unroll
        for (int ct = 0; ct < 4; ++ct)
          acc[rt][ct] = __builtin_amdgcn_mfma_f32_16x16x32_bf16(a[rt], bfr[ct], acc[rt][ct], 0, 0, 0);
    }
    __syncthreads();
    cur ^= 1;
  }

  // ---- epilogue 1: bias+relu -> bf16 exchange (aliases staging bufs) ----
  {
    const float* bp = (wv < 8) ? (btb + wv * Dn) : (bsh + (wv - 8) * Dn);
    float bias[4];
#pragma unroll
    for (int ct = 0; ct < 4; ++ct) bias[ct] = bp[d0 + ct * 16 + r];
    char* ex = smem + (wv << 13);
#pragma unroll
    for (int rt = 0; rt < 4; ++rt)
#pragma unroll
      for (int ct = 0; ct < 4; ++ct) {
        float v0 = fmaxf(acc[rt][ct][0] + bias[ct], 0.f);
        float v1 = fmaxf(acc[rt][ct][1] + bias[ct], 0.f);
        float v2 = fmaxf(acc[rt][ct][2] + bias[ct], 0.f);
        float v3 = fmaxf(acc[rt][ct][3] + bias[ct], 0.f);
        uint2 pk;
        pk.x = (unsigned)f2bf(v0) | ((unsigned)f2bf(v1) << 16);
        pk.y = (unsigned)f2bf(v2) | ((unsigned)f2bf(v3) << 16);
        int col = ct * 16 + r;
        *(uint2*)(ex + swz(col * 128 + rt * 32 + g * 8)) = pk;
      }
  }
  __syncthreads();

  // ---- epilogue 2: gated combine ----
  if (tid < 512) {
    int col = tid & 63, q = tid >> 6;
    short8 v[12];
#pragma unroll
    for (int e = 0; e < 12; ++e)
      v[e] = *(const short8*)(smem + (e << 13) + swz(col * 128 + q * 16));
    unsigned short* os0 = (unsigned short*)(smem + OUTS_OFF);
    unsigned short* os1 = os0 + 64 * 72;
#pragma unroll
    for (int jj = 0; jj < 8; ++jj) {
      int row = q * 8 + jj;
      const float* gp = (const float*)(smem + GSH_OFF + (row << 6));
      float4 ga = ((const float4*)gp)[0];  // t0 task gates (e0..3)
      float4 gb = ((const float4*)gp)[1];  // t0 shared
      float4 gc = ((const float4*)gp)[2];  // t1 task (e4..7)
      float4 gd = ((const float4*)gp)[3];  // t1 shared
      float s0 = ga.x * bf2f((unsigned short)v[0][jj]) + ga.y * bf2f((unsigned short)v[1][jj]) +
                 ga.z * bf2f((unsigned short)v[2][jj]) + ga.w * bf2f((unsigned short)v[3][jj]);
      float s1 = gc.x * bf2f((unsigned short)v[4][jj]) + gc.y * bf2f((unsigned short)v[5][jj]) +
                 gc.z * bf2f((unsigned short)v[6][jj]) + gc.w * bf2f((unsigned short)v[7][jj]);
      float sh0 = bf2f((unsigned short)v[8][jj]), sh1 = bf2f((unsigned short)v[9][jj]);
      float sh2 = bf2f((unsigned short)v[10][jj]), sh3 = bf2f((unsigned short)v[11][jj]);
      s0 += gb.x * sh0 + gb.y * sh1 + gb.z * sh2 + gb.w * sh3;
      s1 += gd.x * sh0 + gd.y * sh1 + gd.z * sh2 + gd.w * sh3;
      os0[row * 72 + col] = f2bf(s0);
      os1[row * 72 + col] = f2bf(s1);
    }
  }
  __syncthreads();

  // ---- epilogue 3: vectorized global writes ----
  if (tid < 512) {
    int row = tid >> 3, cq = tid & 7;
    const unsigned short* os0 = (const unsigned short*)(smem + OUTS_OFF) + row * 72 + cq * 8;
    const unsigned short* os1 = os0 + 64 * 72;
    ushort8 p0 = *(const ushort8*)os0, p1 = *(const ushort8*)os1;
    int b = b0 + row, d = d0 + cq * 8;
    if (MODE == 0) {
      ushort8 pk;
#pragma unroll
      for (int u = 0; u < 8; ++u)
        pk[u] = f2bf(0.5f * (bf2f((unsigned short)p0[u]) + bf2f((unsigned short)p1[u])));
      *(ushort8*)(outn + (size_t)b * Dn + d) = pk;
      int kk2 = d >> 5;
      int nat = ((b & 63) << 6) + ((d & 31) << 1);
      *(ushort8*)(outt + (((size_t)kk2 * 128 + bblk) << 11) + (swz(nat) >> 1)) = pk;
    } else {
      *(ushort8*)(outn + (size_t)b * 1024 + d) = p0;
      *(ushort8*)(outn + (size_t)b * 1024 + 512 + d) = p1;
    }
  }
}

// ============ tower (bf16 input) ============
__global__ __launch_bounds__(256) void tower_kernel(
    const unsigned short* __restrict__ tout,
    const float* __restrict__ tw1, const float* __restrict__ tb1,
    const float* __restrict__ bng, const float* __restrict__ bnb,
    const float* __restrict__ bnm, const float* __restrict__ bnv,
    const float* __restrict__ tw2, const float* __restrict__ tb2,
    const float* __restrict__ tw3, const float* __restrict__ tb3,
    float* __restrict__ out) {
  __shared__ float xsh[8][2 * Dn];
  __shared__ float h1s[8][2 * Hn];
  __shared__ float h2s[8][Hn];
  __shared__ float lg[8][2];
  int tid = threadIdx.x;
  int b0 = blockIdx.x * 8;

  const unsigned short* tb = tout + (size_t)b0 * 1024;
#pragma unroll
  for (int u = 0; u < 4; ++u) {
    int flat = tid * 32 + u * 8;
    ushort8 vv = *(const ushort8*)(tb + flat);
    int bb = flat >> 10, c = flat & 1023;
#pragma unroll
    for (int j = 0; j < 8; ++j) xsh[bb][c + j] = bf2f((unsigned short)vv[j]);
  }
  __syncthreads();

  {
    int j = tid;
    float acc[2][8];
#pragma unroll
    for (int t = 0; t < 2; ++t)
#pragma unroll
      for (int bb = 0; bb < 8; ++bb) acc[t][bb] = 0.f;
    for (int d4 = 0; d4 < Dn / 4; ++d4) {
      int d = d4 * 4;
      float4 xa[8], xb[8];
#pragma unroll
      for (int bb = 0; bb < 8; ++bb) {
        xa[bb] = *(const float4*)&xsh[bb][d];
        xb[bb] = *(const float4*)&xsh[bb][Dn + d];
      }
#pragma unroll
      for (int dd = 0; dd < 4; ++dd) {
        float w0 = tw1[(size_t)(d + dd) * Hn + j];
        float w1 = tw1[(size_t)Dn * Hn + (size_t)(d + dd) * Hn + j];
#pragma unroll
        for (int bb = 0; bb < 8; ++bb) {
          acc[0][bb] += f4c(xa[bb], dd) * w0;
          acc[1][bb] += f4c(xb[bb], dd) * w1;
        }
      }
    }
#pragma unroll
    for (int t = 0; t < 2; ++t) {
      float mu = bnm[t * Hn + j], var = bnv[t * Hn + j];
      float inv = rsqrtf(var + 1e-5f) * bng[t * Hn + j];
      float be = bnb[t * Hn + j];
      float bias = tb1[t * Hn + j];
#pragma unroll
      for (int bb = 0; bb < 8; ++bb) {
        float h = acc[t][bb] + bias;
        h = (h - mu) * inv + be;
        h1s[bb][t * Hn + j] = fmaxf(h, 0.f);
      }
    }
  }
  __syncthreads();

  {
    int t = tid >> 7, g = tid & 127;
    float acc2[8];
#pragma unroll
    for (int bb = 0; bb < 8; ++bb) acc2[bb] = 0.f;
    for (int h4 = 0; h4 < Hn / 4; ++h4) {
      float4 hv[8];
#pragma unroll
      for (int bb = 0; bb < 8; ++bb)
        hv[bb] = *(const float4*)&h1s[bb][t * Hn + h4 * 4];
#pragma unroll
      for (int dd = 0; dd < 4; ++dd) {
        float w = tw2[(size_t)t * Hn * 128 + (size_t)(h4 * 4 + dd) * 128 + g];
#pragma unroll
        for (int bb = 0; bb < 8; ++bb) acc2[bb] += f4c(hv[bb], dd) * w;
      }
    }
    float bias = tb2[t * 128 + g];
#pragma unroll
    for (int bb = 0; bb < 8; ++bb)
      h2s[bb][t * 128 + g] = fmaxf(acc2[bb] + bias, 0.f);
  }
  __syncthreads();

  {
    int wv = tid >> 6, lane = tid & 63;
#pragma unroll
    for (int p = 0; p < 4; ++p) {
      int idx = wv * 4 + p;
      int bb = idx >> 1, t = idx & 1;
      float v = h2s[bb][t * 128 + lane] * tw3[t * 128 + lane] +
                h2s[bb][t * 128 + 64 + lane] * tw3[t * 128 + 64 + lane];
      v += __shfl_xor(v, 1); v += __shfl_xor(v, 2); v += __shfl_xor(v, 4);
      v += __shfl_xor(v, 8); v += __shfl_xor(v, 16); v += __shfl_xor(v, 32);
      if (lane == 0) lg[bb][t] = v + tb3[t];
    }
  }
  __syncthreads();

  if (tid < 8) {
    int b = b0 + tid;
    float ctr = 1.f / (1.f + expf(-lg[tid][0]));
    float cvr = 1.f / (1.f + expf(-lg[tid][1]));
    float cc = ctr * cvr;
    out[b] = ctr;
    out[Bn + b] = cc;
    out[2 * Bn + b] = cc;
  }
}

// ============ launch ============
extern "C" void kernel_launch(void* const* d_in, const int* in_sizes, int n_in,
                              void* d_out, int out_size, void* d_ws, size_t ws_size,
                              hipStream_t stream) {
  const int* sparse   = (const int*)d_in[0];
  const float* dense  = (const float*)d_in[1];
  const float* emb    = (const float*)d_in[2];
  const float* dW     = (const float*)d_in[3];
  const float* db     = (const float*)d_in[4];
  const float* Wt[3]  = {(const float*)d_in[5],  (const float*)d_in[11], (const float*)d_in[17]};
  const float* btb[3] = {(const float*)d_in[6],  (const float*)d_in[12], (const float*)d_in[18]};
  const float* Wsh[3] = {(const float*)d_in[7],  (const float*)d_in[13], (const float*)d_in[19]};
  const float* bsh[3] = {(const float*)d_in[8],  (const float*)d_in[14], (const float*)d_in[20]};
  const float* Wg[3]  = {(const float*)d_in[9],  (const float*)d_in[15], (const float*)d_in[21]};
  const float* bg[3]  = {(const float*)d_in[10], (const float*)d_in[16], (const float*)d_in[22]};
  const float* tw1 = (const float*)d_in[23];
  const float* tb1 = (const float*)d_in[24];
  const float* bng = (const float*)d_in[25];
  const float* bnb = (const float*)d_in[26];
  const float* bnm = (const float*)d_in[27];
  const float* bnv = (const float*)d_in[28];
  const float* tw2 = (const float*)d_in[29];
  const float* tb2 = (const float*)d_in[30];
  const float* tw3 = (const float*)d_in[31];
  const float* tb3 = (const float*)d_in[32];

  // workspace (bf16 unless noted):
  unsigned short* x0n = (unsigned short*)d_ws;            // 8192*960
  unsigned short* x0t = x0n + (size_t)Bn * 960;           // tiled
  unsigned short* x1n = x0t + (size_t)Bn * 960;           // 8192*512
  unsigned short* x1t = x1n + (size_t)Bn * 512;
  unsigned short* toutB = x1t + (size_t)Bn * 512;         // 8192*1024
  float* gatesB = (float*)(toutB + (size_t)Bn * 1024);    // 8192*16 fp32
  unsigned short* Wbt = (unsigned short*)(gatesB + (size_t)Bn * 16);  // 11.8 MB, reused per layer
  unsigned short* x2n = x0n;  // reuse (x0 dead after layer 0)
  unsigned short* x2t = x0t;

  dim3 pGrid(128, 8);

  conv_w<960><<<dim3(30, 8, 12), 256, 0, stream>>>(Wt[0], Wsh[0], Wbt);
  embed_kernel<<<Bn, 256, 0, stream>>>(sparse, dense, emb, dW, db, x0n, x0t);
  gate_kernel<960><<<Bn / 4, 256, 0, stream>>>(x0n, Wg[0], bg[0], gatesB);
  ple_mfma<960, 0><<<pGrid, 768, 0, stream>>>(x0t, gatesB, Wbt, btb[0], bsh[0], x1n, x1t);

  conv_w<512><<<dim3(16, 8, 12), 256, 0, stream>>>(Wt[1], Wsh[1], Wbt);
  gate_kernel<512><<<Bn / 4, 256, 0, stream>>>(x1n, Wg[1], bg[1], gatesB);
  ple_mfma<512, 0><<<pGrid, 768, 0, stream>>>(x1t, gatesB, Wbt, btb[1], bsh[1], x2n, x2t);

  conv_w<512><<<dim3(16, 8, 12), 256, 0, stream>>>(Wt[2], Wsh[2], Wbt);
  gate_kernel<512><<<Bn / 4, 256, 0, stream>>>(x2n, Wg[2], bg[2], gatesB);
  ple_mfma<512, 1><<<pGrid, 768, 0, stream>>>(x2t, gatesB, Wbt, btb[2], bsh[2], toutB, nullptr);

  tower_kernel<<<Bn / 8, 256, 0, stream>>>(toutB, tw1, tb1, bng, bnb, bnm, bnv,
                                           tw2, tb2, tw3, tb3, (float*)d_out);
}

// Round 3
// 384.035 us; speedup vs baseline: 9.7707x; 1.2807x over previous
//
#include <hip/hip_runtime.h>
#include <math.h>

#define Bn 8192
#define INP0 960
#define Dn 512
#define Hn 256
#define TEMP_INV 0.5f

typedef __attribute__((ext_vector_type(8))) short short8;
typedef __attribute__((ext_vector_type(8))) unsigned short ushort8;
typedef __attribute__((ext_vector_type(4))) float f32x4;

__device__ __forceinline__ int swz(int x) { return x ^ ((x >> 3) & 0x70); }

__device__ __forceinline__ unsigned short f2bf(float f) {
  unsigned u = __builtin_bit_cast(unsigned, f);
  u += 0x7FFF + ((u >> 16) & 1);
  return (unsigned short)(u >> 16);
}
__device__ __forceinline__ float bf2f(unsigned short s) {
  unsigned u = ((unsigned)s) << 16;
  return __builtin_bit_cast(float, u);
}
__device__ __forceinline__ void gload16(const void* g, void* l) {
  __builtin_amdgcn_global_load_lds(
      (const __attribute__((address_space(1))) unsigned int*)g,
      (__attribute__((address_space(3))) unsigned int*)l, 16, 0, 0);
}
__device__ __forceinline__ float f4c(const float4& v, int i) {
  return (i == 0) ? v.x : (i == 1) ? v.y : (i == 2) ? v.z : v.w;
}

// ============ weight convert: fp32 (e,k,d) -> bf16 tiled/swizzled [kk][dblk][e][4KB] ============
template <int IN>
__global__ __launch_bounds__(256) void conv_w(const float* __restrict__ Wt,
                                              const float* __restrict__ Ws,
                                              unsigned short* __restrict__ Wbt) {
  __shared__ float T[64][33];
  int kk = blockIdx.x, dblk = blockIdx.y, e = blockIdx.z;
  int t = threadIdx.x;
  const float* base = (e < 8) ? (Wt + (size_t)e * IN * Dn) : (Ws + (size_t)(e - 8) * IN * Dn);
  int k = t >> 3, dq = t & 7;
  const float* gp = base + (size_t)(kk * 32 + k) * Dn + dblk * 64 + dq * 8;
  float4 v0 = *(const float4*)gp, v1 = *(const float4*)(gp + 4);
  T[dq * 8 + 0][k] = v0.x; T[dq * 8 + 1][k] = v0.y; T[dq * 8 + 2][k] = v0.z; T[dq * 8 + 3][k] = v0.w;
  T[dq * 8 + 4][k] = v1.x; T[dq * 8 + 5][k] = v1.y; T[dq * 8 + 6][k] = v1.z; T[dq * 8 + 7][k] = v1.w;
  __syncthreads();
  int L = t * 16;
  int nat = swz(L);
  int d = nat >> 6, k0 = (nat & 63) >> 1;
  ushort8 o;
#pragma unroll
  for (int u = 0; u < 8; ++u) o[u] = f2bf(T[d][k0 + u]);
  *(ushort8*)(Wbt + (((size_t)(kk * 8 + dblk) * 12 + e) << 11) + (L >> 1)) = o;
}

// ============ tower-weight convert: fp32 (t,K,H) -> bf16 tiles [kk][hb][t] ============
template <int K, int H>
__global__ __launch_bounds__(256) void conv_tw(const float* __restrict__ W,
                                               unsigned short* __restrict__ out) {
  __shared__ float T[64][33];
  int kk = blockIdx.x, hb = blockIdx.y, t = blockIdx.z;
  int tid = threadIdx.x;
  const float* base = W + (size_t)t * K * H;
  int k = tid >> 3, dq = tid & 7;
  const float* gp = base + (size_t)(kk * 32 + k) * H + hb * 64 + dq * 8;
  float4 v0 = *(const float4*)gp, v1 = *(const float4*)(gp + 4);
  T[dq * 8 + 0][k] = v0.x; T[dq * 8 + 1][k] = v0.y; T[dq * 8 + 2][k] = v0.z; T[dq * 8 + 3][k] = v0.w;
  T[dq * 8 + 4][k] = v1.x; T[dq * 8 + 5][k] = v1.y; T[dq * 8 + 6][k] = v1.z; T[dq * 8 + 7][k] = v1.w;
  __syncthreads();
  int L = tid * 16;
  int nat = swz(L);
  int c = nat >> 6, k0 = (nat & 63) >> 1;
  ushort8 o;
#pragma unroll
  for (int u = 0; u < 8; ++u) o[u] = f2bf(T[c][k0 + u]);
  const int NHB = H / 64;
  *(ushort8*)(out + (((size_t)(kk * NHB + hb) * 2 + t) << 11) + (L >> 1)) = o;
}

// ============ embedding: writes natural bf16 x0n and tiled/swizzled x0t ============
__global__ __launch_bounds__(256) void embed_kernel(
    const int* __restrict__ sparse, const float* __restrict__ dense,
    const float* __restrict__ emb, const float* __restrict__ dW,
    const float* __restrict__ db,
    unsigned short* __restrict__ xn, unsigned short* __restrict__ xt) {
  int b = blockIdx.x, t = threadIdx.x;
  __shared__ float dfs[10];
  if (t < 10) dfs[t] = dense[b * 10 + t];
  __syncthreads();
  if (t >= 240) return;
  int c = t * 4;
  float v[4];
  if (c < 640) {
    int f = c >> 5, e0 = c & 31;
    int idx = sparse[b * 20 + f];
    const float* ep = emb + ((size_t)f * 1000 + idx) * 32 + e0;
    float4 q = *(const float4*)ep;
    v[0] = q.x; v[1] = q.y; v[2] = q.z; v[3] = q.w;
  } else {
    int j = c - 640;
#pragma unroll
    for (int u = 0; u < 4; ++u) {
      float a = db[j + u];
#pragma unroll
      for (int d = 0; d < 10; ++d) a += dfs[d] * dW[d * 320 + j + u];
      v[u] = a;
    }
  }
  ushort4 pk;
  pk.x = f2bf(v[0]); pk.y = f2bf(v[1]); pk.z = f2bf(v[2]); pk.w = f2bf(v[3]);
  *(ushort4*)(xn + (size_t)b * 960 + c) = pk;
  int kk = c >> 5, bblk = b >> 6;
  int nat = ((b & 63) << 6) + ((c & 31) << 1);
  *(ushort4*)(xt + (((size_t)kk * 128 + bblk) << 11) + (swz(nat) >> 1)) = pk;
}

// ============ gates (reads natural bf16 x) ============
template <int IN>
__global__ __launch_bounds__(256) void gate_kernel(
    const unsigned short* __restrict__ x, const float* __restrict__ Wg,
    const float* __restrict__ bg, float* __restrict__ gates) {
  int tid = threadIdx.x;
  int wv = tid >> 6, lane = tid & 63;
  int b = blockIdx.x * 4 + wv;
  int e = lane & 15, t = e >> 3, eg = e & 7;
  int slice = lane >> 4;
  const unsigned short* xr = x + (size_t)b * IN;
  const float* wr = Wg + (size_t)t * IN * 8 + eg;
  float p = 0.f;
  for (int i = slice * (IN / 4); i < (slice + 1) * (IN / 4); i += 4) {
    ushort4 xv = *(const ushort4*)(xr + i);
    p += bf2f(xv.x) * wr[(size_t)(i + 0) * 8];
    p += bf2f(xv.y) * wr[(size_t)(i + 1) * 8];
    p += bf2f(xv.z) * wr[(size_t)(i + 2) * 8];
    p += bf2f(xv.w) * wr[(size_t)(i + 3) * 8];
  }
  p += __shfl_xor(p, 32);
  p += __shfl_xor(p, 16);
  float z = (p + bg[t * 8 + eg]) * TEMP_INV;
  float m = z;
  m = fmaxf(m, __shfl_xor(m, 1)); m = fmaxf(m, __shfl_xor(m, 2)); m = fmaxf(m, __shfl_xor(m, 4));
  float ex = expf(z - m);
  float s = ex;
  s += __shfl_xor(s, 1); s += __shfl_xor(s, 2); s += __shfl_xor(s, 4);
  if (lane < 16) gates[(size_t)b * 16 + lane] = ex / s;
}

// ============ fused PLE layer: 12 waves, expert-per-wave, MFMA, in-LDS gated combine ============
#define BUFSZ 53248
#define XOFF 49152
#define GSH_OFF 106496
#define OUTS_OFF 110592

template <int IN, int MODE>
__global__ __launch_bounds__(768) void ple_mfma(
    const unsigned short* __restrict__ xt, const float* __restrict__ gates,
    const unsigned short* __restrict__ Wbt,
    const float* __restrict__ btb, const float* __restrict__ bsh,
    unsigned short* __restrict__ outn, unsigned short* __restrict__ outt) {
  __shared__ __align__(16) char smem[129024];
  const int NKv = IN / 32;
  int tid = threadIdx.x;
  int wv = tid >> 6, lane = tid & 63;
  int r = lane & 15, g = lane >> 4;
  int bblk = blockIdx.x, dblk = blockIdx.y;
  int b0 = bblk * 64, d0 = dblk * 64;

  if (tid < 256)
    *(float4*)(smem + GSH_OFF + tid * 16) = *(const float4*)(gates + (size_t)b0 * 16 + tid * 4);

  f32x4 acc[4][4];
#pragma unroll
  for (int i = 0; i < 4; ++i)
#pragma unroll
    for (int j = 0; j < 4; ++j) acc[i][j] = f32x4{0.f, 0.f, 0.f, 0.f};

  const char* wchunk = (const char*)Wbt + (size_t)dblk * 49152;
  const char* xchunk = (const char*)xt + (size_t)bblk * 4096;

  {
    char* lb = smem;
#pragma unroll
    for (int i = 0; i < 4; ++i)
      gload16(wchunk + tid * 16 + i * 12288, lb + tid * 16 + i * 12288);
    if (tid < 256) gload16(xchunk + tid * 16, lb + XOFF + tid * 16);
  }
  __syncthreads();

  int cur = 0;
  for (int kk = 0; kk < NKv; ++kk) {
    if (kk + 1 < NKv) {
      const char* ws = wchunk + (size_t)(kk + 1) * 8 * 49152;
      const char* xs = xchunk + (size_t)(kk + 1) * 128 * 4096;
      char* lb = smem + (cur ^ 1) * BUFSZ;
#pragma unroll
      for (int i = 0; i < 4; ++i)
        gload16(ws + tid * 16 + i * 12288, lb + tid * 16 + i * 12288);
      if (tid < 256) gload16(xs + tid * 16, lb + XOFF + tid * 16);
    }
    {
      const char* lb = smem + cur * BUFSZ;
      const char* xb = lb + XOFF;
      const char* wb = lb + (wv << 12);
      short8 a[4], bfr[4];
#pragma unroll
      for (int rt = 0; rt < 4; ++rt)
        a[rt] = *(const short8*)(xb + swz(((rt * 16 + r) << 6) + (g << 4)));
#pragma unroll
      for (int ct = 0; ct < 4; ++ct)
        bfr[ct] = *(const short8*)(wb + swz(((ct * 16 + r) << 6) + (g << 4)));
#pragma unroll
      for (int rt = 0; rt < 4; ++rt)
#pragma unroll
        for (int ct = 0; ct < 4; ++ct)
          acc[rt][ct] = __builtin_amdgcn_mfma_f32_16x16x32_bf16(a[rt], bfr[ct], acc[rt][ct], 0, 0, 0);
    }
    __syncthreads();
    cur ^= 1;
  }

  {
    const float* bp = (wv < 8) ? (btb + wv * Dn) : (bsh + (wv - 8) * Dn);
    float bias[4];
#pragma unroll
    for (int ct = 0; ct < 4; ++ct) bias[ct] = bp[d0 + ct * 16 + r];
    char* ex = smem + (wv << 13);
#pragma unroll
    for (int rt = 0; rt < 4; ++rt)
#pragma unroll
      for (int ct = 0; ct < 4; ++ct) {
        float v0 = fmaxf(acc[rt][ct][0] + bias[ct], 0.f);
        float v1 = fmaxf(acc[rt][ct][1] + bias[ct], 0.f);
        float v2 = fmaxf(acc[rt][ct][2] + bias[ct], 0.f);
        float v3 = fmaxf(acc[rt][ct][3] + bias[ct], 0.f);
        uint2 pk;
        pk.x = (unsigned)f2bf(v0) | ((unsigned)f2bf(v1) << 16);
        pk.y = (unsigned)f2bf(v2) | ((unsigned)f2bf(v3) << 16);
        int col = ct * 16 + r;
        *(uint2*)(ex + swz(col * 128 + rt * 32 + g * 8)) = pk;
      }
  }
  __syncthreads();

  if (tid < 512) {
    int col = tid & 63, q = tid >> 6;
    short8 v[12];
#pragma unroll
    for (int e = 0; e < 12; ++e)
      v[e] = *(const short8*)(smem + (e << 13) + swz(col * 128 + q * 16));
    unsigned short* os0 = (unsigned short*)(smem + OUTS_OFF);
    unsigned short* os1 = os0 + 64 * 72;
#pragma unroll
    for (int jj = 0; jj < 8; ++jj) {
      int row = q * 8 + jj;
      const float* gp = (const float*)(smem + GSH_OFF + (row << 6));
      float4 ga = ((const float4*)gp)[0];
      float4 gb = ((const float4*)gp)[1];
      float4 gc = ((const float4*)gp)[2];
      float4 gd = ((const float4*)gp)[3];
      float s0 = ga.x * bf2f((unsigned short)v[0][jj]) + ga.y * bf2f((unsigned short)v[1][jj]) +
                 ga.z * bf2f((unsigned short)v[2][jj]) + ga.w * bf2f((unsigned short)v[3][jj]);
      float s1 = gc.x * bf2f((unsigned short)v[4][jj]) + gc.y * bf2f((unsigned short)v[5][jj]) +
                 gc.z * bf2f((unsigned short)v[6][jj]) + gc.w * bf2f((unsigned short)v[7][jj]);
      float sh0 = bf2f((unsigned short)v[8][jj]), sh1 = bf2f((unsigned short)v[9][jj]);
      float sh2 = bf2f((unsigned short)v[10][jj]), sh3 = bf2f((unsigned short)v[11][jj]);
      s0 += gb.x * sh0 + gb.y * sh1 + gb.z * sh2 + gb.w * sh3;
      s1 += gd.x * sh0 + gd.y * sh1 + gd.z * sh2 + gd.w * sh3;
      os0[row * 72 + col] = f2bf(s0);
      os1[row * 72 + col] = f2bf(s1);
    }
  }
  __syncthreads();

  if (tid < 512) {
    int row = tid >> 3, cq = tid & 7;
    const unsigned short* os0 = (const unsigned short*)(smem + OUTS_OFF) + row * 72 + cq * 8;
    const unsigned short* os1 = os0 + 64 * 72;
    ushort8 p0 = *(const ushort8*)os0, p1 = *(const ushort8*)os1;
    int b = b0 + row, d = d0 + cq * 8;
    if (MODE == 0) {
      ushort8 pk;
#pragma unroll
      for (int u = 0; u < 8; ++u)
        pk[u] = f2bf(0.5f * (bf2f((unsigned short)p0[u]) + bf2f((unsigned short)p1[u])));
      *(ushort8*)(outn + (size_t)b * Dn + d) = pk;
      int kk2 = d >> 5;
      int nat = ((b & 63) << 6) + ((d & 31) << 1);
      *(ushort8*)(outt + (((size_t)kk2 * 128 + bblk) << 11) + (swz(nat) >> 1)) = pk;
    } else {
      // per-task tiled layout for tower: tile = ((t*16 + kk2)*128 + bblk)
      int kk2 = d >> 5;
      int nat = ((b & 63) << 6) + ((d & 31) << 1);
      *(ushort8*)(outt + (((size_t)(0 * 16 + kk2) * 128 + bblk) << 11) + (swz(nat) >> 1)) = p0;
      *(ushort8*)(outt + (((size_t)(1 * 16 + kk2) * 128 + bblk) << 11) + (swz(nat) >> 1)) = p1;
    }
  }
}

// ============ fused MFMA tower ============
// 32 rows/block, 256 blocks, 512 thr (8 waves).
// phase1: h1 = relu(BN(tout_t @ tw1_t + tb1))  (K=512, N=2x256)
// phase2: h2 = relu(h1 @ tw2_t + tb2)          (K=256, N=2x128)
// phase3: logit = h2 . tw3_t + tb3 -> sigmoid -> out
#define TWBUF 36864   // [W 32KB][A 4KB]
#define H1OFF 73728   // 32KB of h1 tiles: [(t*8+kk)*2048]

__global__ __launch_bounds__(512) void tower_mfma(
    const unsigned short* __restrict__ toutT,
    const unsigned short* __restrict__ twbt1, const unsigned short* __restrict__ twbt2,
    const float* __restrict__ tb1,
    const float* __restrict__ bng, const float* __restrict__ bnb,
    const float* __restrict__ bnm, const float* __restrict__ bnv,
    const float* __restrict__ tb2, const float* __restrict__ tw3,
    const float* __restrict__ tb3, float* __restrict__ out) {
  __shared__ __align__(16) char smem[106496];
  int tid = threadIdx.x;
  int wv = tid >> 6, lane = tid & 63, r = lane & 15, g = lane >> 4;
  int blk = blockIdx.x;
  int bblk = blk >> 1, sub = blk & 1;
  int b0 = blk * 32;
  char* h1t = smem + H1OFF;

  int t1 = wv >> 2, hb = wv & 3;
  f32x4 acc[2][4];
#pragma unroll
  for (int i = 0; i < 2; ++i)
#pragma unroll
    for (int j = 0; j < 4; ++j) acc[i][j] = f32x4{0.f, 0.f, 0.f, 0.f};

  // ---- phase 1: K=512 over 16 chunks, double-buffered ----
  {
    char* lb = smem;
#pragma unroll
    for (int i = 0; i < 4; ++i)
      gload16((const char*)twbt1 + tid * 16 + i * 8192, lb + tid * 16 + i * 8192);
    if (tid < 256) {
      int tt = tid >> 7, off = (tid & 127) * 16;
      gload16((const char*)toutT + (((size_t)(tt * 16 + 0) * 128 + bblk) << 12) + sub * 2048 + off,
              lb + 32768 + tt * 2048 + off);
    }
  }
  __syncthreads();
  int cur = 0;
  for (int kk = 0; kk < 16; ++kk) {
    if (kk + 1 < 16) {
      char* lb = smem + (cur ^ 1) * TWBUF;
#pragma unroll
      for (int i = 0; i < 4; ++i)
        gload16((const char*)twbt1 + (size_t)(kk + 1) * 32768 + tid * 16 + i * 8192,
                lb + tid * 16 + i * 8192);
      if (tid < 256) {
        int tt = tid >> 7, off = (tid & 127) * 16;
        gload16((const char*)toutT + (((size_t)(tt * 16 + kk + 1) * 128 + bblk) << 12) + sub * 2048 + off,
                lb + 32768 + tt * 2048 + off);
      }
    }
    {
      const char* lb = smem + cur * TWBUF;
      const char* wb = lb + (hb * 2 + t1) * 4096;
      const char* xb = lb + 32768 + t1 * 2048;
      short8 a[2], bfr[4];
#pragma unroll
      for (int rt = 0; rt < 2; ++rt)
        a[rt] = *(const short8*)(xb + swz(((rt * 16 + r) << 6) + (g << 4)));
#pragma unroll
      for (int ct = 0; ct < 4; ++ct)
        bfr[ct] = *(const short8*)(wb + swz(((ct * 16 + r) << 6) + (g << 4)));
#pragma unroll
      for (int rt = 0; rt < 2; ++rt)
#pragma unroll
        for (int ct = 0; ct < 4; ++ct)
          acc[rt][ct] = __builtin_amdgcn_mfma_f32_16x16x32_bf16(a[rt], bfr[ct], acc[rt][ct], 0, 0, 0);
    }
    __syncthreads();
    cur ^= 1;
  }

  // ---- phase 1 epilogue: +tb1, BN, relu -> bf16 h1 tiles ----
  {
#pragma unroll
    for (int ct = 0; ct < 4; ++ct) {
      int h = hb * 64 + ct * 16 + r;
      int idx = t1 * 256 + h;
      float inv = rsqrtf(bnv[idx] + 1e-5f) * bng[idx];
      float mu = bnm[idx], be = bnb[idx], bias = tb1[idx];
      int kk2 = h >> 5, kloc = h & 31;
      char* tile = h1t + (t1 * 8 + kk2) * 2048;
#pragma unroll
      for (int rt = 0; rt < 2; ++rt)
#pragma unroll
        for (int j = 0; j < 4; ++j) {
          int lr = rt * 16 + g * 4 + j;
          float v = acc[rt][ct][j] + bias;
          v = (v - mu) * inv + be;
          v = fmaxf(v, 0.f);
          *(unsigned short*)(tile + swz((lr << 6) + (kloc << 1))) = f2bf(v);
        }
    }
  }
  __syncthreads();

  // ---- phase 2: h2 (waves 0..3), B direct from global (L2-hot) ----
  float* h2x = (float*)smem;  // [ (t*32+lr) * 129 + col ], 33KB (overlays dead buf0)
  if (wv < 4) {
    int t2 = wv >> 1, hb2 = wv & 1;
    f32x4 acc2[2][4];
#pragma unroll
    for (int i = 0; i < 2; ++i)
#pragma unroll
      for (int j = 0; j < 4; ++j) acc2[i][j] = f32x4{0.f, 0.f, 0.f, 0.f};
    for (int kk = 0; kk < 8; ++kk) {
      const char* xb = h1t + (t2 * 8 + kk) * 2048;
      const char* wb = (const char*)twbt2 + ((kk * 2 + hb2) * 2 + t2) * 4096;
      short8 a[2], bfr[4];
#pragma unroll
      for (int rt = 0; rt < 2; ++rt)
        a[rt] = *(const short8*)(xb + swz(((rt * 16 + r) << 6) + (g << 4)));
#pragma unroll
      for (int ct = 0; ct < 4; ++ct)
        bfr[ct] = *(const short8*)(wb + swz(((ct * 16 + r) << 6) + (g << 4)));
#pragma unroll
      for (int rt = 0; rt < 2; ++rt)
#pragma unroll
        for (int ct = 0; ct < 4; ++ct)
          acc2[rt][ct] = __builtin_amdgcn_mfma_f32_16x16x32_bf16(a[rt], bfr[ct], acc2[rt][ct], 0, 0, 0);
    }
#pragma unroll
    for (int ct = 0; ct < 4; ++ct) {
      int col = hb2 * 64 + ct * 16 + r;
      float bias = tb2[t2 * 128 + col];
#pragma unroll
      for (int rt = 0; rt < 2; ++rt)
#pragma unroll
        for (int j = 0; j < 4; ++j) {
          int lr = rt * 16 + g * 4 + j;
          h2x[(t2 * 32 + lr) * 129 + col] = fmaxf(acc2[rt][ct][j] + bias, 0.f);
        }
    }
  }
  __syncthreads();

  // ---- phase 3: logits + sigmoid ----
  float* lgs = (float*)(smem + 40960);  // 64 floats (dead buf1 region)
  if (tid < 64) {
    int t3 = tid >> 5, lr = tid & 31;
    const float* hr = h2x + (t3 * 32 + lr) * 129;
    const float* w3 = tw3 + t3 * 128;
    float s = 0.f;
#pragma unroll 8
    for (int i = 0; i < 128; ++i) s += hr[i] * w3[i];
    lgs[t3 * 32 + lr] = s + tb3[t3];
  }
  __syncthreads();
  if (tid < 32) {
    int b = b0 + tid;
    float ctr = 1.f / (1.f + expf(-lgs[tid]));
    float cvr = 1.f / (1.f + expf(-lgs[32 + tid]));
    float cc = ctr * cvr;
    out[b] = ctr;
    out[Bn + b] = cc;
    out[2 * Bn + b] = cc;
  }
}

// ============ launch ============
extern "C" void kernel_launch(void* const* d_in, const int* in_sizes, int n_in,
                              void* d_out, int out_size, void* d_ws, size_t ws_size,
                              hipStream_t stream) {
  const int* sparse   = (const int*)d_in[0];
  const float* dense  = (const float*)d_in[1];
  const float* emb    = (const float*)d_in[2];
  const float* dW     = (const float*)d_in[3];
  const float* db     = (const float*)d_in[4];
  const float* Wt[3]  = {(const float*)d_in[5],  (const float*)d_in[11], (const float*)d_in[17]};
  const float* btb[3] = {(const float*)d_in[6],  (const float*)d_in[12], (const float*)d_in[18]};
  const float* Wsh[3] = {(const float*)d_in[7],  (const float*)d_in[13], (const float*)d_in[19]};
  const float* bsh[3] = {(const float*)d_in[8],  (const float*)d_in[14], (const float*)d_in[20]};
  const float* Wg[3]  = {(const float*)d_in[9],  (const float*)d_in[15], (const float*)d_in[21]};
  const float* bg[3]  = {(const float*)d_in[10], (const float*)d_in[16], (const float*)d_in[22]};
  const float* tw1 = (const float*)d_in[23];
  const float* tb1 = (const float*)d_in[24];
  const float* bng = (const float*)d_in[25];
  const float* bnb = (const float*)d_in[26];
  const float* bnm = (const float*)d_in[27];
  const float* bnv = (const float*)d_in[28];
  const float* tw2 = (const float*)d_in[29];
  const float* tb2 = (const float*)d_in[30];
  const float* tw3 = (const float*)d_in[31];
  const float* tb3 = (const float*)d_in[32];

  // workspace (bf16 unless noted):
  unsigned short* x0n = (unsigned short*)d_ws;            // 8192*960
  unsigned short* x0t = x0n + (size_t)Bn * 960;
  unsigned short* x1n = x0t + (size_t)Bn * 960;           // 8192*512
  unsigned short* x1t = x1n + (size_t)Bn * 512;
  unsigned short* toutT = x1t + (size_t)Bn * 512;         // 8192*1024, per-task tiled
  float* gatesB = (float*)(toutT + (size_t)Bn * 1024);    // 8192*16 fp32
  unsigned short* Wbt = (unsigned short*)(gatesB + (size_t)Bn * 16);  // 11.8 MB
  unsigned short* twbt1 = Wbt + (size_t)30 * 8 * 12 * 2048;  // 512 KB
  unsigned short* twbt2 = twbt1 + (size_t)2 * 512 * 256;     // 128 KB
  unsigned short* x2n = x0n;
  unsigned short* x2t = x0t;

  dim3 pGrid(128, 8);

  conv_tw<512, 256><<<dim3(16, 4, 2), 256, 0, stream>>>(tw1, twbt1);
  conv_tw<256, 128><<<dim3(8, 2, 2), 256, 0, stream>>>(tw2, twbt2);

  conv_w<960><<<dim3(30, 8, 12), 256, 0, stream>>>(Wt[0], Wsh[0], Wbt);
  embed_kernel<<<Bn, 256, 0, stream>>>(sparse, dense, emb, dW, db, x0n, x0t);
  gate_kernel<960><<<Bn / 4, 256, 0, stream>>>(x0n, Wg[0], bg[0], gatesB);
  ple_mfma<960, 0><<<pGrid, 768, 0, stream>>>(x0t, gatesB, Wbt, btb[0], bsh[0], x1n, x1t);

  conv_w<512><<<dim3(16, 8, 12), 256, 0, stream>>>(Wt[1], Wsh[1], Wbt);
  gate_kernel<512><<<Bn / 4, 256, 0, stream>>>(x1n, Wg[1], bg[1], gatesB);
  ple_mfma<512, 0><<<pGrid, 768, 0, stream>>>(x1t, gatesB, Wbt, btb[1], bsh[1], x2n, x2t);

  conv_w<512><<<dim3(16, 8, 12), 256, 0, stream>>>(Wt[2], Wsh[2], Wbt);
  gate_kernel<512><<<Bn / 4, 256, 0, stream>>>(x2n, Wg[2], bg[2], gatesB);
  ple_mfma<512, 1><<<pGrid, 768, 0, stream>>>(x2t, gatesB, Wbt, btb[2], bsh[2], nullptr, toutT);

  tower_mfma<<<256, 512, 0, stream>>>(toutT, twbt1, twbt2, tb1, bng, bnb, bnm, bnv,
                                      tb2, tw3, tb3, (float*)d_out);
}